// Round 1
// baseline (575.531 us; speedup 1.0000x reference)
//
#include <hip/hip_runtime.h>

// AssociationLayer: masked Sinkhorn (100 iters) + mutual-argmax assignment.
// One block per example; 1024 threads; each thread holds an 8x8 fp32 tile of
// K = exp(10*aff) in registers (interior only -- the births/deaths row/col of
// K is all-ones and handled analytically via scalars u_bd/v_bd).

#define T_MAX   256
#define L_FLAT  (257 * 257)
#define N_ITERS 100
#define LAMBDA_F 10.0f
#define EPS_F    1e-12f
#define RP       264   // padded row length of LDS reduction scratch [32][RP]

__global__ __launch_bounds__(1024) void assoc_sinkhorn_kernel(
    const float* __restrict__ aff,
    const int*   __restrict__ ndet,
    const int*   __restrict__ ntrk,
    float*       __restrict__ out_t,
    float*       __restrict__ out_a)
{
    const int b   = blockIdx.x;
    const int nd  = ndet[b];
    const int nt  = ntrk[b];
    const int tid = threadIdx.x;
    const int tr  = tid >> 5;     // 0..31 row-tile
    const int tc  = tid & 31;     // 0..31 col-tile
    const int r0  = tr << 3;
    const int c0  = tc << 3;

    __shared__ __align__(16) float red[32 * RP];   // 33.8 KB reduction scratch
    __shared__ float uarr[256];
    __shared__ float varr[256];
    __shared__ float rmax_s[256];
    __shared__ float cmax_s[256];
    __shared__ float rhas_s[256];
    __shared__ float chas_s[256];
    __shared__ float supart[4];
    __shared__ float svpart[4];
    __shared__ float sc_ubd;   // u[nt]
    __shared__ float sc_vbd;   // v[nd]

    // ---- load affinity tile, K = exp(lambda*aff) masked to interior ----
    float K[8][8];
    {
        const float* Ab = aff + (size_t)b * (T_MAX * T_MAX);
        #pragma unroll
        for (int i = 0; i < 8; ++i) {
            const int r = r0 + i;
            const float4 x0 = *reinterpret_cast<const float4*>(Ab + (size_t)r * T_MAX + c0);
            const float4 x1 = *reinterpret_cast<const float4*>(Ab + (size_t)r * T_MAX + c0 + 4);
            const float av[8] = {x0.x, x0.y, x0.z, x0.w, x1.x, x1.y, x1.z, x1.w};
            #pragma unroll
            for (int j = 0; j < 8; ++j) {
                const bool interior = (r < nt) && ((c0 + j) < nd);
                K[i][j] = interior ? expf(LAMBDA_F * av[j]) : 0.0f;
            }
        }
    }

    if (tid < 256) {
        varr[tid] = (tid < nd) ? 1.0f : 0.0f;   // v0 = col_valid
        uarr[tid] = 0.0f;
    }
    if (tid == 0) {
        sc_vbd = 1.0f;
        sc_ubd = 0.0f;
        svpart[0] = (float)nd; svpart[1] = 0.f; svpart[2] = 0.f; svpart[3] = 0.f;
        supart[0] = supart[1] = supart[2] = supart[3] = 0.f;
    }
    __syncthreads();

    const int  kA     = (nd + 7) >> 3;          // tc-groups that touch c<nd
    const int  kB     = (nt + 7) >> 3;          // tr-groups that touch r<nt
    const bool active = (r0 < nt) && (c0 < nd); // tile has nonzero K

    for (int it = 0; it < N_ITERS; ++it) {
        // ---- partials of K @ v ----
        if (active) {
            float v8[8];
            #pragma unroll
            for (int j = 0; j < 8; ++j) v8[j] = varr[c0 + j];
            float p[8];
            #pragma unroll
            for (int i = 0; i < 8; ++i) {
                float s = 0.f;
                #pragma unroll
                for (int j = 0; j < 8; ++j) s = fmaf(K[i][j], v8[j], s);
                p[i] = s;
            }
            *reinterpret_cast<float4*>(&red[tc * RP + r0])     = make_float4(p[0], p[1], p[2], p[3]);
            *reinterpret_cast<float4*>(&red[tc * RP + r0 + 4]) = make_float4(p[4], p[5], p[6], p[7]);
        }
        __syncthreads();
        // ---- u update: u[r<nt] = 1/(Sint + v_bd + eps); u_bd = nd/(Sv + v_bd + eps) ----
        if (tid < 256) {
            float s = 0.f;
            for (int k = 0; k < kA; ++k) s += red[k * RP + tid];
            const float unew = (tid < nt) ? 1.0f / (s + sc_vbd + EPS_F) : 0.0f;
            uarr[tid] = unew;
            float w = unew;
            #pragma unroll
            for (int m = 1; m < 64; m <<= 1) w += __shfl_xor(w, m, 64);
            if ((tid & 63) == 0) supart[tid >> 6] = w;
        } else if (tid == 256) {
            const float sv = svpart[0] + svpart[1] + svpart[2] + svpart[3];
            sc_ubd = (float)nd / (sv + sc_vbd + EPS_F);
        }
        __syncthreads();
        // ---- partials of K^T @ u ----
        if (active) {
            float u8[8];
            #pragma unroll
            for (int i = 0; i < 8; ++i) u8[i] = uarr[r0 + i];
            float q[8];
            #pragma unroll
            for (int j = 0; j < 8; ++j) {
                float s = 0.f;
                #pragma unroll
                for (int i = 0; i < 8; ++i) s = fmaf(K[i][j], u8[i], s);
                q[j] = s;
            }
            *reinterpret_cast<float4*>(&red[tr * RP + c0])     = make_float4(q[0], q[1], q[2], q[3]);
            *reinterpret_cast<float4*>(&red[tr * RP + c0 + 4]) = make_float4(q[4], q[5], q[6], q[7]);
        }
        if (tid == 256) {
            const float su = supart[0] + supart[1] + supart[2] + supart[3];
            sc_vbd = (float)nt / (su + sc_ubd + EPS_F);   // v_bd for the NEW v
        }
        __syncthreads();
        // ---- v update: v[c<nd] = 1/(Tint + u_bd + eps) ----
        if (tid < 256) {
            float s = 0.f;
            for (int k = 0; k < kB; ++k) s += red[k * RP + tid];
            const float vnew = (tid < nd) ? 1.0f / (s + sc_ubd + EPS_F) : 0.0f;
            varr[tid] = vnew;
            float w = vnew;
            #pragma unroll
            for (int m = 1; m < 64; m <<= 1) w += __shfl_xor(w, m, 64);
            if ((tid & 63) == 0) svpart[tid >> 6] = w;
        }
        __syncthreads();
    }

    // ================= epilogue =================
    // transport t = u * K * v (overwrite K registers; zero outside interior
    // automatically since uarr/varr are zero there)
    float u8[8], v8[8];
    #pragma unroll
    for (int i = 0; i < 8; ++i) u8[i] = uarr[r0 + i];
    #pragma unroll
    for (int j = 0; j < 8; ++j) v8[j] = varr[c0 + j];
    const float ubd = sc_ubd;
    const float vbd = sc_vbd;
    #pragma unroll
    for (int i = 0; i < 8; ++i) {
        #pragma unroll
        for (int j = 0; j < 8; ++j) K[i][j] = u8[i] * K[i][j] * v8[j];
    }

    // ---- row max (interior t > 0, masked entries are 0, so plain max works) ----
    {
        float p[8];
        #pragma unroll
        for (int i = 0; i < 8; ++i) {
            float m = K[i][0];
            #pragma unroll
            for (int j = 1; j < 8; ++j) m = fmaxf(m, K[i][j]);
            p[i] = m;
        }
        *reinterpret_cast<float4*>(&red[tc * RP + r0])     = make_float4(p[0], p[1], p[2], p[3]);
        *reinterpret_cast<float4*>(&red[tc * RP + r0 + 4]) = make_float4(p[4], p[5], p[6], p[7]);
    }
    __syncthreads();
    if (tid < 256) {
        float m = red[tid];
        for (int k = 1; k < 32; ++k) m = fmaxf(m, red[k * RP + tid]);
        rmax_s[tid] = m;
    }
    __syncthreads();
    // ---- col max ----
    {
        float p[8];
        #pragma unroll
        for (int j = 0; j < 8; ++j) {
            float m = K[0][j];
            #pragma unroll
            for (int i = 1; i < 8; ++i) m = fmaxf(m, K[i][j]);
            p[j] = m;
        }
        *reinterpret_cast<float4*>(&red[tr * RP + c0])     = make_float4(p[0], p[1], p[2], p[3]);
        *reinterpret_cast<float4*>(&red[tr * RP + c0 + 4]) = make_float4(p[4], p[5], p[6], p[7]);
    }
    __syncthreads();
    if (tid < 256) {
        float m = red[tid];
        for (int k = 1; k < 32; ++k) m = fmaxf(m, red[k * RP + tid]);
        cmax_s[tid] = m;
    }
    __syncthreads();

    // ---- mutual argmax bits ----
    unsigned ab[8];
    #pragma unroll
    for (int i = 0; i < 8; ++i) {
        unsigned bits = 0;
        const int r = r0 + i;
        #pragma unroll
        for (int j = 0; j < 8; ++j) {
            const int c = c0 + j;
            if ((r < nt) && (c < nd) && (K[i][j] == rmax_s[r]) && (K[i][j] == cmax_s[c]))
                bits |= (1u << j);
        }
        ab[i] = bits;
    }
    // ---- row has assignment ----
    {
        float p[8];
        #pragma unroll
        for (int i = 0; i < 8; ++i) p[i] = ab[i] ? 1.0f : 0.0f;
        *reinterpret_cast<float4*>(&red[tc * RP + r0])     = make_float4(p[0], p[1], p[2], p[3]);
        *reinterpret_cast<float4*>(&red[tc * RP + r0 + 4]) = make_float4(p[4], p[5], p[6], p[7]);
    }
    __syncthreads();
    if (tid < 256) {
        float m = red[tid];
        for (int k = 1; k < 32; ++k) m = fmaxf(m, red[k * RP + tid]);
        rhas_s[tid] = m;
    }
    __syncthreads();
    // ---- col has assignment ----
    {
        float p[8];
        #pragma unroll
        for (int j = 0; j < 8; ++j) {
            unsigned cb = 0;
            #pragma unroll
            for (int i = 0; i < 8; ++i) cb |= (ab[i] >> j) & 1u;
            p[j] = cb ? 1.0f : 0.0f;
        }
        *reinterpret_cast<float4*>(&red[tr * RP + c0])     = make_float4(p[0], p[1], p[2], p[3]);
        *reinterpret_cast<float4*>(&red[tr * RP + c0 + 4]) = make_float4(p[4], p[5], p[6], p[7]);
    }
    __syncthreads();
    if (tid < 256) {
        float m = red[tid];
        for (int k = 1; k < 32; ++k) m = fmaxf(m, red[k * RP + tid]);
        chas_s[tid] = m;
    }
    __syncthreads();

    // ---- writeout: packed (nt+1)x(nd+1) row-major, zero-padded to L_FLAT ----
    float* Ot = out_t + (size_t)b * L_FLAT;
    float* Oa = out_a + (size_t)b * L_FLAT;
    const int stride = nd + 1;

    // interior
    #pragma unroll
    for (int i = 0; i < 8; ++i) {
        const int r = r0 + i;
        if (r < nt) {
            #pragma unroll
            for (int j = 0; j < 8; ++j) {
                const int c = c0 + j;
                if (c < nd) {
                    const int k = r * stride + c;
                    Ot[k] = K[i][j];
                    Oa[k] = ((ab[i] >> j) & 1u) ? 1.0f : 0.0f;
                }
            }
        }
    }
    // deaths column (c = nd) and births row (r = nt)
    if (tid < 256) {
        if (tid < nt) {
            const int k = tid * stride + nd;
            Ot[k] = uarr[tid] * vbd;                       // t[r][nd] = u[r]*1*v_bd
            Oa[k] = (rhas_s[tid] > 0.0f) ? 0.0f : 1.0f;    // death if no assignment
        }
        if (tid < nd) {
            const int k = nt * stride + tid;
            Ot[k] = ubd * varr[tid];                       // t[nt][c] = u_bd*1*v[c]
            Oa[k] = (chas_s[tid] > 0.0f) ? 0.0f : 1.0f;    // birth if no assignment
        }
    }
    if (tid == 0) {
        const int k = nt * stride + nd;
        Ot[k] = ubd * vbd;
        Oa[k] = 0.0f;
    }
    // zero-fill padding [length, L_FLAT) -- d_out is poisoned each call
    const int length = (nt + 1) * stride;
    for (int k = length + tid; k < L_FLAT; k += 1024) {
        Ot[k] = 0.0f;
        Oa[k] = 0.0f;
    }
}

extern "C" void kernel_launch(void* const* d_in, const int* in_sizes, int n_in,
                              void* d_out, int out_size, void* d_ws, size_t ws_size,
                              hipStream_t stream)
{
    const float* aff  = (const float*)d_in[0];
    const int*   ndet = (const int*)d_in[1];
    const int*   ntrk = (const int*)d_in[2];
    const int    Bn   = in_sizes[1];          // batch = len(num_detections)
    float* out_t = (float*)d_out;
    float* out_a = out_t + (size_t)Bn * L_FLAT;
    assoc_sinkhorn_kernel<<<dim3(Bn), dim3(1024), 0, stream>>>(aff, ndet, ntrk, out_t, out_a);
}

// Round 2
// 446.346 us; speedup vs baseline: 1.2894x; 1.2894x over previous
//
#include <hip/hip_runtime.h>

// AssociationLayer: masked Sinkhorn (100 iters) + mutual-argmax assignment.
// One block per example; 1024 threads; each thread holds an 8x8 fp32 tile of
// K = exp(10*aff) in registers. Births/deaths row/col of K is all-ones and
// handled analytically via scalars u_bd/v_bd kept in registers of tid<256.
//
// R2 changes vs R1 (which was latency-bound on runtime-trip-count stage-2
// reduction loops, ~120cyc dependent ds_read chains, VALUBusy 17%):
//  - stage-2 loops are compile-time (8 / 32) and fully unrolled with
//    independent accumulators -> batched ds_reads, one waitcnt
//  - all tiles write partials (inactive write zeros) so bounds are static
//  - dir1 (K@v) partials pre-reduced over quads with DPP quad_perm
//    (xor1=0xB1, xor2=0x4E) -> only 8 partial rows + 1/4 write traffic
//  - u_bd / v_bd / scalar sums carried in registers of tid<256

#define T_MAX   256
#define L_FLAT  (257 * 257)
#define N_ITERS 100
#define LAMBDA_F 10.0f
#define EPS_F    1e-12f
#define RP       264   // padded row length of LDS reduction scratch [32][RP]

__device__ __forceinline__ float quad_reduce_add(float x) {
    // butterfly over lanes within each quad: xor1 then xor2 (DPP, VALU pipe)
    int t;
    t = __builtin_amdgcn_update_dpp(0, __float_as_int(x), 0xB1, 0xF, 0xF, true);
    x += __int_as_float(t);
    t = __builtin_amdgcn_update_dpp(0, __float_as_int(x), 0x4E, 0xF, 0xF, true);
    x += __int_as_float(t);
    return x;
}

__global__ __launch_bounds__(1024) void assoc_sinkhorn_kernel(
    const float* __restrict__ aff,
    const int*   __restrict__ ndet,
    const int*   __restrict__ ntrk,
    float*       __restrict__ out_t,
    float*       __restrict__ out_a)
{
    const int b   = blockIdx.x;
    const int nd  = ndet[b];
    const int nt  = ntrk[b];
    const int tid = threadIdx.x;
    const int tr  = tid >> 5;     // 0..31 row-tile
    const int tc  = tid & 31;     // 0..31 col-tile
    const int r0  = tr << 3;
    const int c0  = tc << 3;

    __shared__ __align__(16) float red[32 * RP];   // 33.8 KB reduction scratch
    __shared__ float uarr[256];
    __shared__ float varr[256];
    __shared__ float rmax_s[256];
    __shared__ float cmax_s[256];
    __shared__ float rhas_s[256];
    __shared__ float chas_s[256];
    __shared__ float supart[4];
    __shared__ float svpart[4];
    __shared__ float sc_ubd;   // u[nt] (epilogue broadcast)
    __shared__ float sc_vbd;   // v[nd] (epilogue broadcast)

    // ---- load affinity tile, K = exp(lambda*aff) masked to interior ----
    float K[8][8];
    {
        const float* Ab = aff + (size_t)b * (T_MAX * T_MAX);
        #pragma unroll
        for (int i = 0; i < 8; ++i) {
            const int r = r0 + i;
            const float4 x0 = *reinterpret_cast<const float4*>(Ab + (size_t)r * T_MAX + c0);
            const float4 x1 = *reinterpret_cast<const float4*>(Ab + (size_t)r * T_MAX + c0 + 4);
            const float av[8] = {x0.x, x0.y, x0.z, x0.w, x1.x, x1.y, x1.z, x1.w};
            #pragma unroll
            for (int j = 0; j < 8; ++j) {
                const bool interior = (r < nt) && ((c0 + j) < nd);
                K[i][j] = interior ? expf(LAMBDA_F * av[j]) : 0.0f;
            }
        }
    }

    if (tid < 256) {
        varr[tid] = (tid < nd) ? 1.0f : 0.0f;   // v0 = col_valid (interior part)
    }
    if (tid == 0) {
        svpart[0] = (float)nd; svpart[1] = 0.f; svpart[2] = 0.f; svpart[3] = 0.f;
    }
    __syncthreads();

    const bool red_thread = (tid < 256);
    float vbd = 1.0f;   // v[nd], carried in registers of tid<256
    float ubd = 0.0f;   // u[nt]
    const bool quad_writer = ((tc & 3) == 0);
    const int  qrow = tc >> 2;   // 0..7 partial row for dir1

    for (int it = 0; it < N_ITERS; ++it) {
        // ---- dir1: partials of K @ v, quad-pre-reduced over tc%4 ----
        {
            float4 va = *reinterpret_cast<const float4*>(&varr[c0]);
            float4 vb = *reinterpret_cast<const float4*>(&varr[c0 + 4]);
            const float v8[8] = {va.x, va.y, va.z, va.w, vb.x, vb.y, vb.z, vb.w};
            float p[8];
            #pragma unroll
            for (int i = 0; i < 8; ++i) {
                float s = 0.f;
                #pragma unroll
                for (int j = 0; j < 8; ++j) s = fmaf(K[i][j], v8[j], s);
                p[i] = quad_reduce_add(s);
            }
            if (quad_writer) {
                *reinterpret_cast<float4*>(&red[qrow * RP + r0])     = make_float4(p[0], p[1], p[2], p[3]);
                *reinterpret_cast<float4*>(&red[qrow * RP + r0 + 4]) = make_float4(p[4], p[5], p[6], p[7]);
            }
        }
        __syncthreads();
        // ---- u update (tid<256): u[r<nt] = 1/(Sint + vbd + eps) ----
        if (red_thread) {
            float s0 = 0.f, s1 = 0.f;
            #pragma unroll
            for (int g = 0; g < 8; g += 2) {
                s0 += red[g * RP + tid];
                s1 += red[(g + 1) * RP + tid];
            }
            const float s = s0 + s1;
            const float svo = svpart[0] + svpart[1] + svpart[2] + svpart[3];
            ubd = (float)nd / (svo + vbd + EPS_F);
            const float unew = (tid < nt) ? 1.0f / (s + vbd + EPS_F) : 0.0f;
            uarr[tid] = unew;
            float w = unew;
            #pragma unroll
            for (int m = 1; m < 64; m <<= 1) w += __shfl_xor(w, m, 64);
            if ((tid & 63) == 0) supart[tid >> 6] = w;
        }
        __syncthreads();
        // ---- dir2: partials of K^T @ u (reduction over tr: via LDS) ----
        {
            float4 ua = *reinterpret_cast<const float4*>(&uarr[r0]);
            float4 ub = *reinterpret_cast<const float4*>(&uarr[r0 + 4]);
            const float u8[8] = {ua.x, ua.y, ua.z, ua.w, ub.x, ub.y, ub.z, ub.w};
            float q[8];
            #pragma unroll
            for (int j = 0; j < 8; ++j) {
                float s = 0.f;
                #pragma unroll
                for (int i = 0; i < 8; ++i) s = fmaf(K[i][j], u8[i], s);
                q[j] = s;
            }
            *reinterpret_cast<float4*>(&red[tr * RP + c0])     = make_float4(q[0], q[1], q[2], q[3]);
            *reinterpret_cast<float4*>(&red[tr * RP + c0 + 4]) = make_float4(q[4], q[5], q[6], q[7]);
        }
        __syncthreads();
        // ---- v update (tid<256): v[c<nd] = 1/(Tint + ubd + eps) ----
        if (red_thread) {
            float s0 = 0.f, s1 = 0.f, s2 = 0.f, s3 = 0.f;
            #pragma unroll
            for (int k = 0; k < 32; k += 4) {
                s0 += red[k * RP + tid];
                s1 += red[(k + 1) * RP + tid];
                s2 += red[(k + 2) * RP + tid];
                s3 += red[(k + 3) * RP + tid];
            }
            const float s = (s0 + s1) + (s2 + s3);
            const float vnew = (tid < nd) ? 1.0f / (s + ubd + EPS_F) : 0.0f;
            varr[tid] = vnew;
            float w = vnew;
            #pragma unroll
            for (int m = 1; m < 64; m <<= 1) w += __shfl_xor(w, m, 64);
            if ((tid & 63) == 0) svpart[tid >> 6] = w;
            const float su = supart[0] + supart[1] + supart[2] + supart[3];
            vbd = (float)nt / (su + ubd + EPS_F);
        }
        __syncthreads();
    }

    if (tid == 0) { sc_ubd = ubd; sc_vbd = vbd; }
    __syncthreads();

    // ================= epilogue =================
    // transport t = u * K * v (overwrite K registers; zero outside interior
    // automatically since uarr/varr are zero there)
    float u8[8], v8[8];
    #pragma unroll
    for (int i = 0; i < 8; ++i) u8[i] = uarr[r0 + i];
    #pragma unroll
    for (int j = 0; j < 8; ++j) v8[j] = varr[c0 + j];
    const float ubd_f = sc_ubd;
    const float vbd_f = sc_vbd;
    #pragma unroll
    for (int i = 0; i < 8; ++i) {
        #pragma unroll
        for (int j = 0; j < 8; ++j) K[i][j] = u8[i] * K[i][j] * v8[j];
    }

    // ---- row max (interior t > 0, masked entries are 0, so plain max works) ----
    {
        float p[8];
        #pragma unroll
        for (int i = 0; i < 8; ++i) {
            float m = K[i][0];
            #pragma unroll
            for (int j = 1; j < 8; ++j) m = fmaxf(m, K[i][j]);
            p[i] = m;
        }
        *reinterpret_cast<float4*>(&red[tc * RP + r0])     = make_float4(p[0], p[1], p[2], p[3]);
        *reinterpret_cast<float4*>(&red[tc * RP + r0 + 4]) = make_float4(p[4], p[5], p[6], p[7]);
    }
    __syncthreads();
    if (tid < 256) {
        float m = red[tid];
        #pragma unroll
        for (int k = 1; k < 32; ++k) m = fmaxf(m, red[k * RP + tid]);
        rmax_s[tid] = m;
    }
    __syncthreads();
    // ---- col max ----
    {
        float p[8];
        #pragma unroll
        for (int j = 0; j < 8; ++j) {
            float m = K[0][j];
            #pragma unroll
            for (int i = 1; i < 8; ++i) m = fmaxf(m, K[i][j]);
            p[j] = m;
        }
        *reinterpret_cast<float4*>(&red[tr * RP + c0])     = make_float4(p[0], p[1], p[2], p[3]);
        *reinterpret_cast<float4*>(&red[tr * RP + c0 + 4]) = make_float4(p[4], p[5], p[6], p[7]);
    }
    __syncthreads();
    if (tid < 256) {
        float m = red[tid];
        #pragma unroll
        for (int k = 1; k < 32; ++k) m = fmaxf(m, red[k * RP + tid]);
        cmax_s[tid] = m;
    }
    __syncthreads();

    // ---- mutual argmax bits ----
    unsigned ab[8];
    #pragma unroll
    for (int i = 0; i < 8; ++i) {
        unsigned bits = 0;
        const int r = r0 + i;
        #pragma unroll
        for (int j = 0; j < 8; ++j) {
            const int c = c0 + j;
            if ((r < nt) && (c < nd) && (K[i][j] == rmax_s[r]) && (K[i][j] == cmax_s[c]))
                bits |= (1u << j);
        }
        ab[i] = bits;
    }
    // ---- row has assignment ----
    {
        float p[8];
        #pragma unroll
        for (int i = 0; i < 8; ++i) p[i] = ab[i] ? 1.0f : 0.0f;
        *reinterpret_cast<float4*>(&red[tc * RP + r0])     = make_float4(p[0], p[1], p[2], p[3]);
        *reinterpret_cast<float4*>(&red[tc * RP + r0 + 4]) = make_float4(p[4], p[5], p[6], p[7]);
    }
    __syncthreads();
    if (tid < 256) {
        float m = red[tid];
        #pragma unroll
        for (int k = 1; k < 32; ++k) m = fmaxf(m, red[k * RP + tid]);
        rhas_s[tid] = m;
    }
    __syncthreads();
    // ---- col has assignment ----
    {
        float p[8];
        #pragma unroll
        for (int j = 0; j < 8; ++j) {
            unsigned cb = 0;
            #pragma unroll
            for (int i = 0; i < 8; ++i) cb |= (ab[i] >> j) & 1u;
            p[j] = cb ? 1.0f : 0.0f;
        }
        *reinterpret_cast<float4*>(&red[tr * RP + c0])     = make_float4(p[0], p[1], p[2], p[3]);
        *reinterpret_cast<float4*>(&red[tr * RP + c0 + 4]) = make_float4(p[4], p[5], p[6], p[7]);
    }
    __syncthreads();
    if (tid < 256) {
        float m = red[tid];
        #pragma unroll
        for (int k = 1; k < 32; ++k) m = fmaxf(m, red[k * RP + tid]);
        chas_s[tid] = m;
    }
    __syncthreads();

    // ---- writeout: packed (nt+1)x(nd+1) row-major, zero-padded to L_FLAT ----
    float* Ot = out_t + (size_t)b * L_FLAT;
    float* Oa = out_a + (size_t)b * L_FLAT;
    const int stride = nd + 1;

    // interior
    #pragma unroll
    for (int i = 0; i < 8; ++i) {
        const int r = r0 + i;
        if (r < nt) {
            #pragma unroll
            for (int j = 0; j < 8; ++j) {
                const int c = c0 + j;
                if (c < nd) {
                    const int k = r * stride + c;
                    Ot[k] = K[i][j];
                    Oa[k] = ((ab[i] >> j) & 1u) ? 1.0f : 0.0f;
                }
            }
        }
    }
    // deaths column (c = nd) and births row (r = nt)
    if (tid < 256) {
        if (tid < nt) {
            const int k = tid * stride + nd;
            Ot[k] = uarr[tid] * vbd_f;                     // t[r][nd] = u[r]*1*v_bd
            Oa[k] = (rhas_s[tid] > 0.0f) ? 0.0f : 1.0f;    // death if no assignment
        }
        if (tid < nd) {
            const int k = nt * stride + tid;
            Ot[k] = ubd_f * varr[tid];                     // t[nt][c] = u_bd*1*v[c]
            Oa[k] = (chas_s[tid] > 0.0f) ? 0.0f : 1.0f;    // birth if no assignment
        }
    }
    if (tid == 0) {
        const int k = nt * stride + nd;
        Ot[k] = ubd_f * vbd_f;
        Oa[k] = 0.0f;
    }
    // zero-fill padding [length, L_FLAT) -- d_out is poisoned each call
    const int length = (nt + 1) * stride;
    for (int k = length + tid; k < L_FLAT; k += 1024) {
        Ot[k] = 0.0f;
        Oa[k] = 0.0f;
    }
}

extern "C" void kernel_launch(void* const* d_in, const int* in_sizes, int n_in,
                              void* d_out, int out_size, void* d_ws, size_t ws_size,
                              hipStream_t stream)
{
    const float* aff  = (const float*)d_in[0];
    const int*   ndet = (const int*)d_in[1];
    const int*   ntrk = (const int*)d_in[2];
    const int    Bn   = in_sizes[1];          // batch = len(num_detections)
    float* out_t = (float*)d_out;
    float* out_a = out_t + (size_t)Bn * L_FLAT;
    assoc_sinkhorn_kernel<<<dim3(Bn), dim3(1024), 0, stream>>>(aff, ndet, ntrk, out_t, out_a);
}

// Round 3
// 444.627 us; speedup vs baseline: 1.2944x; 1.0039x over previous
//
#include <hip/hip_runtime.h>

// AssociationLayer: masked Sinkhorn (100 iters) + mutual-argmax assignment.
// R3 layout: wave w owns rows 16w..16w+15. Lane l (rg=l&3, cg=l>>2) owns a
// 4-row x 16-col strip: rows 16w+4rg+i (i<4), cols 16cg+j (j<16).
//  - dir1 (K@v): row-reduce fully in-wave (ror4,ror8 DPP + xor16 swizzle +
//    xor32 shfl) -> u stays in registers, no barrier.
//  - dir2 (K^T@u): rg-reduce is quad-local (2 quad_perm DPP, pure VALU),
//    one contiguous ds_write_b128 per wave -> stage2 sums only 16 rows.
//  - 2 barriers/iter (was 4). Scalars u_bd/v_bd/sums carried in registers;
//    sigma-v partials double-buffered (svpart[2][4]) to avoid a WAR race.

#define T_MAX   256
#define L_FLAT  (257 * 257)
#define N_ITERS 100
#define LAMBDA_F 10.0f
#define EPS_F    1e-12f

#define QX1  0xB1   // quad_perm xor1
#define QX2  0x4E   // quad_perm xor2
#define ROR4 0x124  // row_ror:4
#define ROR8 0x128  // row_ror:8

template<int CTRL>
__device__ __forceinline__ float dpp_addf(float x) {
    int t = __builtin_amdgcn_update_dpp(0, __float_as_int(x), CTRL, 0xF, 0xF, true);
    return x + __int_as_float(t);
}
template<int CTRL>
__device__ __forceinline__ float dpp_maxf(float x) {
    int t = __builtin_amdgcn_update_dpp(0, __float_as_int(x), CTRL, 0xF, 0xF, true);
    return fmaxf(x, __int_as_float(t));
}
template<int CTRL>
__device__ __forceinline__ int dpp_ori(int x) {
    int t = __builtin_amdgcn_update_dpp(0, x, CTRL, 0xF, 0xF, true);
    return x | t;
}
__device__ __forceinline__ float swz16_addf(float x) {
    return x + __int_as_float(__builtin_amdgcn_ds_swizzle(__float_as_int(x), 0x401F));
}
__device__ __forceinline__ float swz16_maxf(float x) {
    return fmaxf(x, __int_as_float(__builtin_amdgcn_ds_swizzle(__float_as_int(x), 0x401F)));
}
__device__ __forceinline__ int swz16_ori(int x) {
    return x | __builtin_amdgcn_ds_swizzle(x, 0x401F);
}
__device__ __forceinline__ float sel4(float a, float b, float c, float d, int rg) {
    float lo = (rg & 1) ? b : a;
    float hi = (rg & 1) ? d : c;
    return (rg & 2) ? hi : lo;
}

__global__ __launch_bounds__(1024) void assoc_sinkhorn_kernel(
    const float* __restrict__ aff,
    const int*   __restrict__ ndet,
    const int*   __restrict__ ntrk,
    float*       __restrict__ out_t,
    float*       __restrict__ out_a)
{
    const int b   = blockIdx.x;
    const int nd  = ndet[b];
    const int nt  = ntrk[b];
    const int tid = threadIdx.x;
    const int w   = tid >> 6;     // wave 0..15 -> rows 16w..16w+15
    const int l   = tid & 63;
    const int rg  = l & 3;        // row subgroup within wave (quad axis)
    const int cg  = l >> 2;       // col group 0..15
    const int R0  = (w << 4) + (rg << 2);  // lane's 4 rows: R0..R0+3
    const int C0  = cg << 4;               // lane's 16 cols: C0..C0+15

    __shared__ __align__(16) float red[16 * 256];  // per-wave dir2 partials, 16KB
    __shared__ __align__(16) float varr[256];
    __shared__ __align__(16) float cmax_s[256];
    __shared__ __align__(16) float supart[16];
    __shared__ __align__(16) float svpart[2][4];
    __shared__ float sc_vbd;
    __shared__ float sc_ubd;

    // ---- load K = exp(lambda*aff), masked to interior ----
    float K[4][16];
    {
        const float* Ab = aff + (size_t)b * (T_MAX * T_MAX);
        #pragma unroll
        for (int i = 0; i < 4; ++i) {
            const int r = R0 + i;
            const float* row = Ab + (size_t)r * T_MAX + C0;
            #pragma unroll
            for (int k = 0; k < 4; ++k) {
                const float4 x = *reinterpret_cast<const float4*>(row + 4 * k);
                const float a4[4] = {x.x, x.y, x.z, x.w};
                #pragma unroll
                for (int e = 0; e < 4; ++e) {
                    const int j = 4 * k + e;
                    const bool interior = (r < nt) && ((C0 + j) < nd);
                    K[i][j] = interior ? expf(LAMBDA_F * a4[e]) : 0.0f;
                }
            }
        }
    }

    if (tid < 256) varr[tid] = (tid < nd) ? 1.0f : 0.0f;
    if (tid == 0) {
        sc_vbd = 1.0f;
        svpart[0][0] = (float)nd; svpart[0][1] = 0.f; svpart[0][2] = 0.f; svpart[0][3] = 0.f;
    }
    __syncthreads();

    float u[4] = {0.f, 0.f, 0.f, 0.f};
    float vbd_reg = 1.0f;   // stage2-carried v_bd (valid in tid<256)

    for (int it = 0; it < N_ITERS; ++it) {
        // ================= dir1: u update (wave-local) =================
        const float vbd = sc_vbd;
        float v[16];
        {
            const float4 a0 = *reinterpret_cast<const float4*>(&varr[C0]);
            const float4 a1 = *reinterpret_cast<const float4*>(&varr[C0 + 4]);
            const float4 a2 = *reinterpret_cast<const float4*>(&varr[C0 + 8]);
            const float4 a3 = *reinterpret_cast<const float4*>(&varr[C0 + 12]);
            v[0]=a0.x; v[1]=a0.y; v[2]=a0.z; v[3]=a0.w;
            v[4]=a1.x; v[5]=a1.y; v[6]=a1.z; v[7]=a1.w;
            v[8]=a2.x; v[9]=a2.y; v[10]=a2.z; v[11]=a2.w;
            v[12]=a3.x; v[13]=a3.y; v[14]=a3.z; v[15]=a3.w;
        }
        float p[4];
        #pragma unroll
        for (int i = 0; i < 4; ++i) {
            float s = 0.f;
            #pragma unroll
            for (int j = 0; j < 16; ++j) s = fmaf(K[i][j], v[j], s);
            p[i] = s;
        }
        // reduce over cg (16 same-rg lanes): 2 DPP rors + xor16 + xor32
        #pragma unroll
        for (int i = 0; i < 4; ++i) p[i] = dpp_addf<ROR4>(p[i]);
        #pragma unroll
        for (int i = 0; i < 4; ++i) p[i] = dpp_addf<ROR8>(p[i]);
        #pragma unroll
        for (int i = 0; i < 4; ++i) p[i] = swz16_addf(p[i]);
        #pragma unroll
        for (int i = 0; i < 4; ++i) p[i] += __shfl_xor(p[i], 32, 64);
        #pragma unroll
        for (int i = 0; i < 4; ++i)
            u[i] = ((R0 + i) < nt) ? 1.0f / (p[i] + vbd + EPS_F) : 0.0f;

        // wave-Sigma(u): quad reduce over rg (values cg-invariant already)
        {
            float su = (u[0] + u[1]) + (u[2] + u[3]);
            su = dpp_addf<QX1>(su);
            su = dpp_addf<QX2>(su);
            if (l == 0) supart[w] = su;
        }

        // ================= dir2: K^T @ u partials =================
        float q[16];
        #pragma unroll
        for (int j = 0; j < 16; ++j) {
            float s = fmaf(K[0][j], u[0], 0.f);
            s = fmaf(K[1][j], u[1], s);
            s = fmaf(K[2][j], u[2], s);
            q[j] = fmaf(K[3][j], u[3], s);
        }
        #pragma unroll
        for (int j = 0; j < 16; ++j) q[j] = dpp_addf<QX1>(q[j]);
        #pragma unroll
        for (int j = 0; j < 16; ++j) q[j] = dpp_addf<QX2>(q[j]);
        // lane rg writes float4 #rg of its 16 (contiguous 1KB per wave)
        {
            float4 o;
            o.x = sel4(q[0], q[4], q[8],  q[12], rg);
            o.y = sel4(q[1], q[5], q[9],  q[13], rg);
            o.z = sel4(q[2], q[6], q[10], q[14], rg);
            o.w = sel4(q[3], q[7], q[11], q[15], rg);
            *reinterpret_cast<float4*>(&red[w * 256 + C0 + (rg << 2)]) = o;
        }
        __syncthreads();   // barrier A

        // ================= stage2: v update (tid<256) =================
        if (tid < 256) {
            const int p_rd = it & 1;
            const float4 sv4 = *reinterpret_cast<const float4*>(&svpart[p_rd][0]);
            const float Sv = (sv4.x + sv4.y) + (sv4.z + sv4.w);
            const float ubd = (float)nd / (Sv + vbd_reg + EPS_F);

            float s0 = 0.f, s1 = 0.f, s2 = 0.f, s3 = 0.f;
            #pragma unroll
            for (int k = 0; k < 16; k += 4) {
                s0 += red[k * 256 + tid];
                s1 += red[(k + 1) * 256 + tid];
                s2 += red[(k + 2) * 256 + tid];
                s3 += red[(k + 3) * 256 + tid];
            }
            const float s = (s0 + s1) + (s2 + s3);

            const float4 p0 = *reinterpret_cast<const float4*>(&supart[0]);
            const float4 p1 = *reinterpret_cast<const float4*>(&supart[4]);
            const float4 p2 = *reinterpret_cast<const float4*>(&supart[8]);
            const float4 p3 = *reinterpret_cast<const float4*>(&supart[12]);
            const float Su = ((p0.x+p0.y)+(p0.z+p0.w)) + ((p1.x+p1.y)+(p1.z+p1.w))
                           + ((p2.x+p2.y)+(p2.z+p2.w)) + ((p3.x+p3.y)+(p3.z+p3.w));

            const float vn = (tid < nd) ? 1.0f / (s + ubd + EPS_F) : 0.0f;
            varr[tid] = vn;

            const float vbd_new = (float)nt / (Su + ubd + EPS_F);
            vbd_reg = vbd_new;
            if (tid == 0) { sc_vbd = vbd_new; sc_ubd = ubd; }

            // Sigma(v) over the 4 stage2 waves -> double-buffered partials
            float sv = vn;
            sv = dpp_addf<QX1>(sv);
            sv = dpp_addf<QX2>(sv);
            sv = dpp_addf<ROR4>(sv);
            sv = dpp_addf<ROR8>(sv);
            sv = swz16_addf(sv);
            sv += __shfl_xor(sv, 32, 64);
            if (l == 0) svpart[p_rd ^ 1][w] = sv;
        }
        __syncthreads();   // barrier B
    }

    // ================= epilogue =================
    const float vbdF = sc_vbd;
    const float ubdF = sc_ubd;
    float v[16];
    {
        const float4 a0 = *reinterpret_cast<const float4*>(&varr[C0]);
        const float4 a1 = *reinterpret_cast<const float4*>(&varr[C0 + 4]);
        const float4 a2 = *reinterpret_cast<const float4*>(&varr[C0 + 8]);
        const float4 a3 = *reinterpret_cast<const float4*>(&varr[C0 + 12]);
        v[0]=a0.x; v[1]=a0.y; v[2]=a0.z; v[3]=a0.w;
        v[4]=a1.x; v[5]=a1.y; v[6]=a1.z; v[7]=a1.w;
        v[8]=a2.x; v[9]=a2.y; v[10]=a2.z; v[11]=a2.w;
        v[12]=a3.x; v[13]=a3.y; v[14]=a3.z; v[15]=a3.w;
    }
    // t = u*K*v (overwrite K)
    #pragma unroll
    for (int i = 0; i < 4; ++i) {
        #pragma unroll
        for (int j = 0; j < 16; ++j) K[i][j] = u[i] * K[i][j] * v[j];
    }

    // rowmax: in-lane over 16 cols, then cg-reduce (in-wave, no LDS)
    float m[4];
    #pragma unroll
    for (int i = 0; i < 4; ++i) {
        float mm = K[i][0];
        #pragma unroll
        for (int j = 1; j < 16; ++j) mm = fmaxf(mm, K[i][j]);
        m[i] = mm;
    }
    #pragma unroll
    for (int i = 0; i < 4; ++i) m[i] = dpp_maxf<ROR4>(m[i]);
    #pragma unroll
    for (int i = 0; i < 4; ++i) m[i] = dpp_maxf<ROR8>(m[i]);
    #pragma unroll
    for (int i = 0; i < 4; ++i) m[i] = swz16_maxf(m[i]);
    #pragma unroll
    for (int i = 0; i < 4; ++i) m[i] = fmaxf(m[i], __shfl_xor(m[i], 32, 64));

    // colmax: in-lane over 4 rows, quad-reduce, wave partial -> LDS
    {
        float cmx[16];
        #pragma unroll
        for (int j = 0; j < 16; ++j)
            cmx[j] = fmaxf(fmaxf(K[0][j], K[1][j]), fmaxf(K[2][j], K[3][j]));
        #pragma unroll
        for (int j = 0; j < 16; ++j) cmx[j] = dpp_maxf<QX1>(cmx[j]);
        #pragma unroll
        for (int j = 0; j < 16; ++j) cmx[j] = dpp_maxf<QX2>(cmx[j]);
        float4 o;
        o.x = sel4(cmx[0], cmx[4], cmx[8],  cmx[12], rg);
        o.y = sel4(cmx[1], cmx[5], cmx[9],  cmx[13], rg);
        o.z = sel4(cmx[2], cmx[6], cmx[10], cmx[14], rg);
        o.w = sel4(cmx[3], cmx[7], cmx[11], cmx[15], rg);
        *reinterpret_cast<float4*>(&red[w * 256 + C0 + (rg << 2)]) = o;
    }
    __syncthreads();
    if (tid < 256) {
        float mm = red[tid];
        #pragma unroll
        for (int k = 1; k < 16; ++k) mm = fmaxf(mm, red[k * 256 + tid]);
        cmax_s[tid] = mm;
    }
    __syncthreads();

    // mutual argmax bits
    float cm[16];
    {
        const float4 a0 = *reinterpret_cast<const float4*>(&cmax_s[C0]);
        const float4 a1 = *reinterpret_cast<const float4*>(&cmax_s[C0 + 4]);
        const float4 a2 = *reinterpret_cast<const float4*>(&cmax_s[C0 + 8]);
        const float4 a3 = *reinterpret_cast<const float4*>(&cmax_s[C0 + 12]);
        cm[0]=a0.x; cm[1]=a0.y; cm[2]=a0.z; cm[3]=a0.w;
        cm[4]=a1.x; cm[5]=a1.y; cm[6]=a1.z; cm[7]=a1.w;
        cm[8]=a2.x; cm[9]=a2.y; cm[10]=a2.z; cm[11]=a2.w;
        cm[12]=a3.x; cm[13]=a3.y; cm[14]=a3.z; cm[15]=a3.w;
    }
    unsigned bits[4];
    #pragma unroll
    for (int i = 0; i < 4; ++i) {
        unsigned bi = 0;
        const int r = R0 + i;
        #pragma unroll
        for (int j = 0; j < 16; ++j) {
            const int c = C0 + j;
            if ((r < nt) && (c < nd) && (K[i][j] == m[i]) && (K[i][j] == cm[j]))
                bi |= (1u << j);
        }
        bits[i] = bi;
    }
    // rhas: in-wave OR over cg
    int rh[4];
    #pragma unroll
    for (int i = 0; i < 4; ++i) rh[i] = bits[i] ? 1 : 0;
    #pragma unroll
    for (int i = 0; i < 4; ++i) rh[i] = dpp_ori<ROR4>(rh[i]);
    #pragma unroll
    for (int i = 0; i < 4; ++i) rh[i] = dpp_ori<ROR8>(rh[i]);
    #pragma unroll
    for (int i = 0; i < 4; ++i) rh[i] = swz16_ori(rh[i]);
    #pragma unroll
    for (int i = 0; i < 4; ++i) rh[i] |= __shfl_xor(rh[i], 32, 64);

    // chas: quad-reduce OR, wave partial (as float 0/1) -> red (safe: all
    // stage-2 reads of the colmax partials completed before last barrier)
    {
        const unsigned anyb = bits[0] | bits[1] | bits[2] | bits[3];
        float ch[16];
        #pragma unroll
        for (int j = 0; j < 16; ++j) ch[j] = ((anyb >> j) & 1u) ? 1.0f : 0.0f;
        #pragma unroll
        for (int j = 0; j < 16; ++j) ch[j] = dpp_maxf<QX1>(ch[j]);
        #pragma unroll
        for (int j = 0; j < 16; ++j) ch[j] = dpp_maxf<QX2>(ch[j]);
        float4 o;
        o.x = sel4(ch[0], ch[4], ch[8],  ch[12], rg);
        o.y = sel4(ch[1], ch[5], ch[9],  ch[13], rg);
        o.z = sel4(ch[2], ch[6], ch[10], ch[14], rg);
        o.w = sel4(ch[3], ch[7], ch[11], ch[15], rg);
        *reinterpret_cast<float4*>(&red[w * 256 + C0 + (rg << 2)]) = o;
    }
    __syncthreads();

    float* Ot = out_t + (size_t)b * L_FLAT;
    float* Oa = out_a + (size_t)b * L_FLAT;
    const int stride = nd + 1;

    // births row (r = nt) + corner
    if (tid < 256) {
        float c = red[tid];
        #pragma unroll
        for (int k = 1; k < 16; ++k) c = fmaxf(c, red[k * 256 + tid]);
        if (tid < nd) {
            const int kk = nt * stride + tid;
            Ot[kk] = ubdF * varr[tid];
            Oa[kk] = (c > 0.0f) ? 0.0f : 1.0f;
        }
    }
    if (tid == 0) {
        const int kk = nt * stride + nd;
        Ot[kk] = ubdF * vbdF;
        Oa[kk] = 0.0f;
    }
    // deaths column (c = nd): lanes cg==0 own rows R0..R0+3 uniquely
    if (cg == 0) {
        #pragma unroll
        for (int i = 0; i < 4; ++i) {
            const int r = R0 + i;
            if (r < nt) {
                const int kk = r * stride + nd;
                Ot[kk] = u[i] * vbdF;
                Oa[kk] = rh[i] ? 0.0f : 1.0f;
            }
        }
    }
    // interior
    #pragma unroll
    for (int i = 0; i < 4; ++i) {
        const int r = R0 + i;
        if (r < nt) {
            const int base = r * stride;
            #pragma unroll
            for (int j = 0; j < 16; ++j) {
                const int c = C0 + j;
                if (c < nd) {
                    Ot[base + c] = K[i][j];
                    Oa[base + c] = ((bits[i] >> j) & 1u) ? 1.0f : 0.0f;
                }
            }
        }
    }
    // zero-fill padding [length, L_FLAT)
    const int length = (nt + 1) * stride;
    for (int k = length + tid; k < L_FLAT; k += 1024) {
        Ot[k] = 0.0f;
        Oa[k] = 0.0f;
    }
}

extern "C" void kernel_launch(void* const* d_in, const int* in_sizes, int n_in,
                              void* d_out, int out_size, void* d_ws, size_t ws_size,
                              hipStream_t stream)
{
    const float* aff  = (const float*)d_in[0];
    const int*   ndet = (const int*)d_in[1];
    const int*   ntrk = (const int*)d_in[2];
    const int    Bn   = in_sizes[1];
    float* out_t = (float*)d_out;
    float* out_a = out_t + (size_t)Bn * L_FLAT;
    assoc_sinkhorn_kernel<<<dim3(Bn), dim3(1024), 0, stream>>>(aff, ndet, ntrk, out_t, out_a);
}